// Round 3
// baseline (190.181 us; speedup 1.0000x reference)
//
#include <hip/hip_runtime.h>
#include <math.h>

#define NV 778
#define NVP 780            // padded per-batch PK stride (2 sentinel slots)
#define NJ 16
#define NCOMP 24
#define NBETA 10
#define FC 1554
#define NA 32
#define NB 8
#define NOBJ 16384
#define VD (NV*3)          // 2334
#define BCH 584            // ceil(VD/4) row-chunks per batch for k_blend

// ---------------- Kernel 1: fused pose + blendshapes (unchanged from R1).
__global__ __launch_bounds__(256) void k_blend(
    const float* __restrict__ hp, const float* __restrict__ pca,
    const float* __restrict__ vt, const float* __restrict__ sd,
    const float* __restrict__ pd, const float* __restrict__ beta,
    float* __restrict__ VS, float* __restrict__ VP,
    float* __restrict__ sRg, float* __restrict__ pen)
{
    int b = blockIdx.x / BCH, c = blockIdx.x % BCH;
    int t = threadIdx.x;
    int wid = t >> 6, lane = t & 63;
    __shared__ float h45[45];
    __shared__ float sR[NJ*9];
    __shared__ float spf[135];

    if (t < 45) {
        float acc = 0.0f;
        #pragma unroll
        for (int k = 0; k < NCOMP; ++k) acc += hp[b*30 + 6 + k] * pca[k*45 + t];
        h45[t] = acc;
    }
    __syncthreads();
    if (t < NJ) {
        float rx, ry, rz;
        if (t == 0) { rx = hp[b*30+3]; ry = hp[b*30+4]; rz = hp[b*30+5]; }
        else        { rx = h45[(t-1)*3]; ry = h45[(t-1)*3+1]; rz = h45[(t-1)*3+2]; }
        float th = sqrtf(rx*rx + ry*ry + rz*rz + 1e-16f);
        float kx = rx/th, ky = ry/th, kz = rz/th;
        float cc = cosf(th), s = sinf(th), o = 1.0f - cc;
        float R[9];
        R[0] = cc + o*kx*kx;     R[1] = -s*kz + o*kx*ky;  R[2] =  s*ky + o*kx*kz;
        R[3] =  s*kz + o*ky*kx;  R[4] = cc + o*ky*ky;     R[5] = -s*kx + o*ky*kz;
        R[6] = -s*ky + o*kz*kx;  R[7] =  s*kx + o*kz*ky;  R[8] = cc + o*kz*kz;
        #pragma unroll
        for (int i = 0; i < 9; ++i) sR[t*9+i] = R[i];
        if (c == 0) {
            #pragma unroll
            for (int i = 0; i < 9; ++i) sRg[b*(NJ*9) + t*9 + i] = R[i];
        }
    }
    __syncthreads();
    if (t < 135) {
        int mn = t % 9;
        float d = (mn == 0 || mn == 4 || mn == 8) ? 1.0f : 0.0f;
        spf[t] = sR[9 + t] - d;
    }
    if (b == 0 && c == 0 && t == 0) *pen = 0.0f;
    __syncthreads();

    int r = c*4 + wid;                 // row within batch: v*3 + d
    if (r < VD) {
        const float* p  = pd + r * 135;
        float accP = p[lane] * spf[lane] + p[lane+64] * spf[lane+64];
        accP += (lane < 7) ? p[lane+128] * spf[lane+128] : 0.0f;

        float accS = (lane < NBETA) ? sd[r*NBETA + lane] * beta[b*NBETA + lane] : 0.0f;

        #pragma unroll
        for (int off = 32; off; off >>= 1) {
            accP += __shfl_down(accP, off, 64);
            accS += __shfl_down(accS, off, 64);
        }
        if (lane == 0) {
            float vs = vt[r] + accS;
            VS[b*VD + r] = vs;
            VP[b*VD + r] = vs + accP;
        }
    }
}

// ---------------- Kernel 2: joints + chain + LBS + face normals + contact.
// PK now written with per-batch stride NVP=780; slots 778/779 get w=1e30
// sentinels so k_nn's 4x195 chunk loop needs no guards.
__global__ __launch_bounds__(1024) void k_skel(
    const float* __restrict__ hp, const float* __restrict__ sRg,
    const float* __restrict__ Jreg, const float* __restrict__ VS,
    const float* __restrict__ VP, const float* __restrict__ W,
    const int* __restrict__ faces, const float* __restrict__ aw,
    const int* __restrict__ afi,
    float* __restrict__ verts, float4* __restrict__ PK,
    float* __restrict__ NRM, float* __restrict__ contact)
{
    int b = blockIdx.x, t = threadIdx.x;
    int lane = t & 63, wid = t >> 6;        // wid 0..15
    __shared__ float sR[NJ*9];
    __shared__ float sJ[NJ*3];
    __shared__ float4 sA4[NJ*3];            // A rows as {r0,r1,r2,t}
    __shared__ float sv[VD];
    __shared__ float sn[VD];

    if (t < NJ*9) sR[t] = sRg[b*NJ*9 + t];
    if (t < 2) PK[b*NVP + NV + t] = make_float4(0.f, 0.f, 0.f, 1e30f);
    for (int i = t; i < VD; i += 1024) sn[i] = 0.0f;

    // joints: wave wid owns joint wid (16 waves -> 16 joints in parallel)
    {
        float a0 = 0.0f, a1 = 0.0f, a2 = 0.0f;
        for (int v = lane; v < NV; v += 64) {
            const float* p = VS + b*VD + v*3;
            float w = Jreg[wid*NV + v];
            a0 += w*p[0]; a1 += w*p[1]; a2 += w*p[2];
        }
        #pragma unroll
        for (int off = 32; off; off >>= 1) {
            a0 += __shfl_down(a0, off, 64);
            a1 += __shfl_down(a1, off, 64);
            a2 += __shfl_down(a2, off, 64);
        }
        if (lane == 0) {
            sJ[wid*3+0] = a0; sJ[wid*3+1] = a1; sJ[wid*3+2] = a2;
        }
    }
    __syncthreads();

    // kinematic chain: thread m (0..2) owns row m of all transforms
    if (t < 3) {
        const int par[NJ] = {-1,0,1,2,0,4,5,0,7,8,0,10,11,0,13,14};
        int m = t;
        float Tr[NJ][3], Tt[NJ];
        Tr[0][0] = sR[m*3+0]; Tr[0][1] = sR[m*3+1]; Tr[0][2] = sR[m*3+2];
        Tt[0] = sJ[m];
        #pragma unroll
        for (int j = 1; j < NJ; ++j) {
            int p = par[j];
            float t0 = sJ[j*3+0] - sJ[p*3+0];
            float t1 = sJ[j*3+1] - sJ[p*3+1];
            float t2 = sJ[j*3+2] - sJ[p*3+2];
            float a0 = Tr[p][0], a1 = Tr[p][1], a2 = Tr[p][2];
            #pragma unroll
            for (int n = 0; n < 3; ++n)
                Tr[j][n] = a0*sR[j*9+n] + a1*sR[j*9+3+n] + a2*sR[j*9+6+n];
            Tt[j] = a0*t0 + a1*t1 + a2*t2 + Tt[p];
        }
        #pragma unroll
        for (int j = 0; j < NJ; ++j) {
            float corr = Tr[j][0]*sJ[j*3] + Tr[j][1]*sJ[j*3+1] + Tr[j][2]*sJ[j*3+2];
            sA4[j*3 + m] = make_float4(Tr[j][0], Tr[j][1], Tr[j][2], Tt[j] - corr);
        }
    }
    __syncthreads();

    // LBS (1 iter: threads 778..1023 idle)
    float tx = hp[b*30+0], ty = hp[b*30+1], tz = hp[b*30+2];
    for (int v = t; v < NV; v += 1024) {
        float4 r0 = make_float4(0,0,0,0), r1 = make_float4(0,0,0,0), r2 = make_float4(0,0,0,0);
        const float* w = W + v * NJ;
        for (int j = 0; j < NJ; ++j) {
            float wj = w[j];
            float4 A0 = sA4[j*3+0], A1 = sA4[j*3+1], A2 = sA4[j*3+2];
            r0.x += wj*A0.x; r0.y += wj*A0.y; r0.z += wj*A0.z; r0.w += wj*A0.w;
            r1.x += wj*A1.x; r1.y += wj*A1.y; r1.z += wj*A1.z; r1.w += wj*A1.w;
            r2.x += wj*A2.x; r2.y += wj*A2.y; r2.z += wj*A2.z; r2.w += wj*A2.w;
        }
        int i = b*NV + v;
        float px = VP[b*VD + v*3], py = VP[b*VD + v*3+1], pz = VP[b*VD + v*3+2];
        float x = r0.x*px + r0.y*py + r0.z*pz + r0.w + tx;
        float y = r1.x*px + r1.y*py + r1.z*pz + r1.w + ty;
        float z = r2.x*px + r2.y*py + r2.z*pz + r2.w + tz;
        sv[v*3] = x; sv[v*3+1] = y; sv[v*3+2] = z;
        verts[i*3] = x; verts[i*3+1] = y; verts[i*3+2] = z;
        PK[b*NVP + v] = make_float4(x, y, z, 0.5f*(x*x + y*y + z*z));
    }
    __syncthreads();

    // face normals into LDS accumulator
    for (int f = t; f < FC; f += 1024) {
        int i0 = faces[f*3], i1 = faces[f*3+1], i2 = faces[f*3+2];
        float ax = sv[i1*3+0]-sv[i0*3+0], ay = sv[i1*3+1]-sv[i0*3+1], az = sv[i1*3+2]-sv[i0*3+2];
        float bx = sv[i2*3+0]-sv[i0*3+0], by = sv[i2*3+1]-sv[i0*3+1], bz = sv[i2*3+2]-sv[i0*3+2];
        float cx = ay*bz - az*by, cy = az*bx - ax*bz, cz = ax*by - ay*bx;
        atomicAdd(&sn[i0*3+0], cx); atomicAdd(&sn[i0*3+1], cy); atomicAdd(&sn[i0*3+2], cz);
        atomicAdd(&sn[i1*3+0], cx); atomicAdd(&sn[i1*3+1], cy); atomicAdd(&sn[i1*3+2], cz);
        atomicAdd(&sn[i2*3+0], cx); atomicAdd(&sn[i2*3+1], cy); atomicAdd(&sn[i2*3+2], cz);
    }
    __syncthreads();

    // outputs: normals + contact candidates
    for (int i = t; i < VD; i += 1024) NRM[b*VD + i] = sn[i];
    if (t < NA*3) {
        int a = t / 3, d = t % 3;
        float acc = 0.0f;
        #pragma unroll
        for (int k = 0; k < 3; ++k)
            acc += aw[a*3 + k] * sv[afi[a*3 + k]*3 + d];
        contact[b*NA*3 + t] = acc;
    }
}

// ---------------- Kernel 3: NN search, scalar-cache vertex stream.
// Inner-loop vertex address is wave-uniform (block-derived base + uniform j),
// so the backend can issue s_load_dwordx4 through the scalar K$ (12.5 KB/batch,
// fits sL1) -- no LDS traffic, no VMEM per pair; VALU-issue-bound.
// 4 contiguous 195-chunks (2 sentinel slots, w=1e30); ascending strict-<
// combine preserves jnp.argmin first-index semantics exactly.
__global__ __launch_bounds__(256) void k_nn(const float* __restrict__ obj,
                                            const float4* __restrict__ PK,
                                            const float* __restrict__ NRM,
                                            float* __restrict__ cmap,
                                            float* __restrict__ pen)
{
    int b = blockIdx.x >> 6;
    int n = (blockIdx.x & 63) * 256 + threadIdx.x;
    int t = threadIdx.x, lane = t & 63;
    int base = b * NV;

    const float4* __restrict__ P0 = PK + b*NVP;
    const float4* __restrict__ P1 = P0 + 195;
    const float4* __restrict__ P2 = P0 + 390;
    const float4* __restrict__ P3 = P0 + 585;

    const float* o = obj + (b*NOBJ + n)*3;
    float ox = o[0], oy = o[1], oz = o[2];

    float s0 = 1e30f, s1 = 1e30f, s2 = 1e30f, s3 = 1e30f;
    int j0 = 0, j1 = 195, j2 = 390, j3 = 585;
    #pragma unroll 2
    for (int j = 0; j < 195; ++j) {
        {
            float4 v = P0[j];
            float s = fmaf(-ox, v.x, v.w); s = fmaf(-oy, v.y, s); s = fmaf(-oz, v.z, s);
            if (s < s0) { s0 = s; j0 = j; }
        }
        {
            float4 v = P1[j];
            float s = fmaf(-ox, v.x, v.w); s = fmaf(-oy, v.y, s); s = fmaf(-oz, v.z, s);
            if (s < s1) { s1 = s; j1 = j + 195; }
        }
        {
            float4 v = P2[j];
            float s = fmaf(-ox, v.x, v.w); s = fmaf(-oy, v.y, s); s = fmaf(-oz, v.z, s);
            if (s < s2) { s2 = s; j2 = j + 390; }
        }
        {
            float4 v = P3[j];
            float s = fmaf(-ox, v.x, v.w); s = fmaf(-oy, v.y, s); s = fmaf(-oz, v.z, s);
            if (s < s3) { s3 = s; j3 = j + 585; }
        }
    }
    // combine in ascending index order, strict < => first-index tie-break
    if (s1 < s0) { s0 = s1; j0 = j1; }
    if (s2 < s0) { s0 = s2; j0 = j2; }
    if (s3 < s0) { s0 = s3; j0 = j3; }

    float osq = ox*ox + oy*oy + oz*oz;
    float d2 = 2.0f * s0 + osq;
    cmap[b*NOBJ + n] = 2.0f / (1.0f + __expf(100.0f * d2));

    float4 qq = P0[j0];
    float nx = NRM[(base + j0)*3 + 0];
    float ny = NRM[(base + j0)*3 + 1];
    float nz = NRM[(base + j0)*3 + 2];
    float dotp = (qq.x - ox)*nx + (qq.y - oy)*ny + (qq.z - oz)*nz;
    float p = (dotp > 0.0f) ? d2 : 0.0f;
    for (int off = 32; off; off >>= 1) p += __shfl_down(p, off, 64);
    __shared__ float wsum[4];
    if (lane == 0) wsum[t >> 6] = p;
    __syncthreads();
    if (t == 0) atomicAdd(pen, (wsum[0] + wsum[1] + wsum[2] + wsum[3]) * (1.0f / NB));
}

extern "C" void kernel_launch(void* const* d_in, const int* in_sizes, int n_in,
                              void* d_out, int out_size, void* d_ws, size_t ws_size,
                              hipStream_t stream)
{
    const float* hp    = (const float*)d_in[0];
    const float* obj   = (const float*)d_in[1];
    const float* beta  = (const float*)d_in[2];
    const float* vt    = (const float*)d_in[3];
    const float* sd    = (const float*)d_in[4];
    const float* pd    = (const float*)d_in[5];
    const float* Jreg  = (const float*)d_in[6];
    const float* W     = (const float*)d_in[7];
    const float* pca   = (const float*)d_in[8];
    const float* aw    = (const float*)d_in[9];
    const int*   faces = (const int*)d_in[10];
    const int*   afi   = (const int*)d_in[11];

    float* out     = (float*)d_out;
    float* cmap    = out;                          // 131072
    float* pen     = out + NB*NOBJ;                // 1
    float* verts   = out + NB*NOBJ + 1;            // 18672
    float* contact = out + NB*NOBJ + 1 + NB*NV*3;  // 768

    float* ws   = (float*)d_ws;
    float4* PK  = (float4*)ws;        // NB*NVP float4 (16B-aligned at base)
    float* NRM  = ws + NB*NVP*4;      // NB*VD
    float* VS   = NRM + NB*VD;        // NB*VD
    float* VP   = VS + NB*VD;         // NB*VD
    float* sRg  = VP + NB*VD;         // NB*144

    k_blend<<<NB*BCH, 256, 0, stream>>>(hp, pca, vt, sd, pd, beta, VS, VP, sRg, pen);
    k_skel <<<NB, 1024, 0, stream>>>(hp, sRg, Jreg, VS, VP, W, faces, aw, afi,
                                     verts, PK, NRM, contact);
    k_nn   <<<NB*64, 256, 0, stream>>>(obj, PK, NRM, cmap, pen);
}

// Round 4
// 147.807 us; speedup vs baseline: 1.2867x; 1.2867x over previous
//
#include <hip/hip_runtime.h>
#include <math.h>

#define NV 778
#define NVP 780            // padded per-batch PK stride (2 sentinel slots)
#define NJ 16
#define NCOMP 24
#define NBETA 10
#define FC 1554
#define NA 32
#define NB 8
#define NOBJ 16384
#define VD (NV*3)          // 2334
#define BCH 584            // ceil(VD/4) row-chunks per batch for k_blend

// ---------------- Kernel 1: fused pose + blendshapes (unchanged, proven).
__global__ __launch_bounds__(256) void k_blend(
    const float* __restrict__ hp, const float* __restrict__ pca,
    const float* __restrict__ vt, const float* __restrict__ sd,
    const float* __restrict__ pd, const float* __restrict__ beta,
    float* __restrict__ VS, float* __restrict__ VP,
    float* __restrict__ sRg, float* __restrict__ pen)
{
    int b = blockIdx.x / BCH, c = blockIdx.x % BCH;
    int t = threadIdx.x;
    int wid = t >> 6, lane = t & 63;
    __shared__ float h45[45];
    __shared__ float sR[NJ*9];
    __shared__ float spf[135];

    if (t < 45) {
        float acc = 0.0f;
        #pragma unroll
        for (int k = 0; k < NCOMP; ++k) acc += hp[b*30 + 6 + k] * pca[k*45 + t];
        h45[t] = acc;
    }
    __syncthreads();
    if (t < NJ) {
        float rx, ry, rz;
        if (t == 0) { rx = hp[b*30+3]; ry = hp[b*30+4]; rz = hp[b*30+5]; }
        else        { rx = h45[(t-1)*3]; ry = h45[(t-1)*3+1]; rz = h45[(t-1)*3+2]; }
        float th = sqrtf(rx*rx + ry*ry + rz*rz + 1e-16f);
        float kx = rx/th, ky = ry/th, kz = rz/th;
        float cc = cosf(th), s = sinf(th), o = 1.0f - cc;
        float R[9];
        R[0] = cc + o*kx*kx;     R[1] = -s*kz + o*kx*ky;  R[2] =  s*ky + o*kx*kz;
        R[3] =  s*kz + o*ky*kx;  R[4] = cc + o*ky*ky;     R[5] = -s*kx + o*ky*kz;
        R[6] = -s*ky + o*kz*kx;  R[7] =  s*kx + o*kz*ky;  R[8] = cc + o*kz*kz;
        #pragma unroll
        for (int i = 0; i < 9; ++i) sR[t*9+i] = R[i];
        if (c == 0) {
            #pragma unroll
            for (int i = 0; i < 9; ++i) sRg[b*(NJ*9) + t*9 + i] = R[i];
        }
    }
    __syncthreads();
    if (t < 135) {
        int mn = t % 9;
        float d = (mn == 0 || mn == 4 || mn == 8) ? 1.0f : 0.0f;
        spf[t] = sR[9 + t] - d;
    }
    if (b == 0 && c == 0 && t == 0) *pen = 0.0f;
    __syncthreads();

    int r = c*4 + wid;                 // row within batch: v*3 + d
    if (r < VD) {
        const float* p  = pd + r * 135;
        float accP = p[lane] * spf[lane] + p[lane+64] * spf[lane+64];
        accP += (lane < 7) ? p[lane+128] * spf[lane+128] : 0.0f;

        float accS = (lane < NBETA) ? sd[r*NBETA + lane] * beta[b*NBETA + lane] : 0.0f;

        #pragma unroll
        for (int off = 32; off; off >>= 1) {
            accP += __shfl_down(accP, off, 64);
            accS += __shfl_down(accS, off, 64);
        }
        if (lane == 0) {
            float vs = vt[r] + accS;
            VS[b*VD + r] = vs;
            VP[b*VD + r] = vs + accP;
        }
    }
}

// ---------------- Kernel 2: joints + chain + LBS + face normals + contact.
// PK written with per-batch stride NVP=780; slots 778/779 get w=1e30
// sentinels so k_nn's chunk loops need no guards.
__global__ __launch_bounds__(1024) void k_skel(
    const float* __restrict__ hp, const float* __restrict__ sRg,
    const float* __restrict__ Jreg, const float* __restrict__ VS,
    const float* __restrict__ VP, const float* __restrict__ W,
    const int* __restrict__ faces, const float* __restrict__ aw,
    const int* __restrict__ afi,
    float* __restrict__ verts, float4* __restrict__ PK,
    float* __restrict__ NRM, float* __restrict__ contact)
{
    int b = blockIdx.x, t = threadIdx.x;
    int lane = t & 63, wid = t >> 6;        // wid 0..15
    __shared__ float sR[NJ*9];
    __shared__ float sJ[NJ*3];
    __shared__ float4 sA4[NJ*3];            // A rows as {r0,r1,r2,t}
    __shared__ float sv[VD];
    __shared__ float sn[VD];

    if (t < NJ*9) sR[t] = sRg[b*NJ*9 + t];
    if (t < 2) PK[b*NVP + NV + t] = make_float4(0.f, 0.f, 0.f, 1e30f);
    for (int i = t; i < VD; i += 1024) sn[i] = 0.0f;

    // joints: wave wid owns joint wid (16 waves -> 16 joints in parallel)
    {
        float a0 = 0.0f, a1 = 0.0f, a2 = 0.0f;
        for (int v = lane; v < NV; v += 64) {
            const float* p = VS + b*VD + v*3;
            float w = Jreg[wid*NV + v];
            a0 += w*p[0]; a1 += w*p[1]; a2 += w*p[2];
        }
        #pragma unroll
        for (int off = 32; off; off >>= 1) {
            a0 += __shfl_down(a0, off, 64);
            a1 += __shfl_down(a1, off, 64);
            a2 += __shfl_down(a2, off, 64);
        }
        if (lane == 0) {
            sJ[wid*3+0] = a0; sJ[wid*3+1] = a1; sJ[wid*3+2] = a2;
        }
    }
    __syncthreads();

    // kinematic chain: thread m (0..2) owns row m of all transforms
    if (t < 3) {
        const int par[NJ] = {-1,0,1,2,0,4,5,0,7,8,0,10,11,0,13,14};
        int m = t;
        float Tr[NJ][3], Tt[NJ];
        Tr[0][0] = sR[m*3+0]; Tr[0][1] = sR[m*3+1]; Tr[0][2] = sR[m*3+2];
        Tt[0] = sJ[m];
        #pragma unroll
        for (int j = 1; j < NJ; ++j) {
            int p = par[j];
            float t0 = sJ[j*3+0] - sJ[p*3+0];
            float t1 = sJ[j*3+1] - sJ[p*3+1];
            float t2 = sJ[j*3+2] - sJ[p*3+2];
            float a0 = Tr[p][0], a1 = Tr[p][1], a2 = Tr[p][2];
            #pragma unroll
            for (int n = 0; n < 3; ++n)
                Tr[j][n] = a0*sR[j*9+n] + a1*sR[j*9+3+n] + a2*sR[j*9+6+n];
            Tt[j] = a0*t0 + a1*t1 + a2*t2 + Tt[p];
        }
        #pragma unroll
        for (int j = 0; j < NJ; ++j) {
            float corr = Tr[j][0]*sJ[j*3] + Tr[j][1]*sJ[j*3+1] + Tr[j][2]*sJ[j*3+2];
            sA4[j*3 + m] = make_float4(Tr[j][0], Tr[j][1], Tr[j][2], Tt[j] - corr);
        }
    }
    __syncthreads();

    // LBS (1 iter: threads 778..1023 idle)
    float tx = hp[b*30+0], ty = hp[b*30+1], tz = hp[b*30+2];
    for (int v = t; v < NV; v += 1024) {
        float4 r0 = make_float4(0,0,0,0), r1 = make_float4(0,0,0,0), r2 = make_float4(0,0,0,0);
        const float* w = W + v * NJ;
        for (int j = 0; j < NJ; ++j) {
            float wj = w[j];
            float4 A0 = sA4[j*3+0], A1 = sA4[j*3+1], A2 = sA4[j*3+2];
            r0.x += wj*A0.x; r0.y += wj*A0.y; r0.z += wj*A0.z; r0.w += wj*A0.w;
            r1.x += wj*A1.x; r1.y += wj*A1.y; r1.z += wj*A1.z; r1.w += wj*A1.w;
            r2.x += wj*A2.x; r2.y += wj*A2.y; r2.z += wj*A2.z; r2.w += wj*A2.w;
        }
        int i = b*NV + v;
        float px = VP[b*VD + v*3], py = VP[b*VD + v*3+1], pz = VP[b*VD + v*3+2];
        float x = r0.x*px + r0.y*py + r0.z*pz + r0.w + tx;
        float y = r1.x*px + r1.y*py + r1.z*pz + r1.w + ty;
        float z = r2.x*px + r2.y*py + r2.z*pz + r2.w + tz;
        sv[v*3] = x; sv[v*3+1] = y; sv[v*3+2] = z;
        verts[i*3] = x; verts[i*3+1] = y; verts[i*3+2] = z;
        PK[b*NVP + v] = make_float4(x, y, z, 0.5f*(x*x + y*y + z*z));
    }
    __syncthreads();

    // face normals into LDS accumulator
    for (int f = t; f < FC; f += 1024) {
        int i0 = faces[f*3], i1 = faces[f*3+1], i2 = faces[f*3+2];
        float ax = sv[i1*3+0]-sv[i0*3+0], ay = sv[i1*3+1]-sv[i0*3+1], az = sv[i1*3+2]-sv[i0*3+2];
        float bx = sv[i2*3+0]-sv[i0*3+0], by = sv[i2*3+1]-sv[i0*3+1], bz = sv[i2*3+2]-sv[i0*3+2];
        float cx = ay*bz - az*by, cy = az*bx - ax*bz, cz = ax*by - ay*bx;
        atomicAdd(&sn[i0*3+0], cx); atomicAdd(&sn[i0*3+1], cy); atomicAdd(&sn[i0*3+2], cz);
        atomicAdd(&sn[i1*3+0], cx); atomicAdd(&sn[i1*3+1], cy); atomicAdd(&sn[i1*3+2], cz);
        atomicAdd(&sn[i2*3+0], cx); atomicAdd(&sn[i2*3+1], cy); atomicAdd(&sn[i2*3+2], cz);
    }
    __syncthreads();

    // outputs: normals + contact candidates
    for (int i = t; i < VD; i += 1024) NRM[b*VD + i] = sn[i];
    if (t < NA*3) {
        int a = t / 3, d = t % 3;
        float acc = 0.0f;
        #pragma unroll
        for (int k = 0; k < 3; ++k)
            acc += aw[a*3 + k] * sv[afi[a*3 + k]*3 + d];
        contact[b*NA*3 + t] = acc;
    }
}

// ---------------- Kernel 3: NN search, LDS-broadcast, 2 obj points/thread.
// k_nn is LDS-read-throughput bound: cost = waves/CU x 780 ds_read_b128.
// 2 points/thread -> 256 blocks (1/CU, 4 waves/CU instead of 8) halves the
// per-CU LDS stream; each b128 read feeds both points. 2 chunks x 2 points
// give 4 independent min-chains (ILP); ascending-chunk strict-< combine
// preserves jnp.argmin first-index semantics exactly.
__global__ __launch_bounds__(256) void k_nn(const float* __restrict__ obj,
                                            const float4* __restrict__ PK,
                                            const float* __restrict__ NRM,
                                            float* __restrict__ cmap,
                                            float* __restrict__ pen)
{
    int t = threadIdx.x, lane = t & 63;
    int b = blockIdx.x >> 5;                       // 32 blocks per batch
    int n0 = (blockIdx.x & 31) * 512 + t;          // first point
    int n1 = n0 + 256;                             // second point
    int base = b * NV;

    __shared__ float4 sPK[NVP];
    for (int i = t; i < NVP; i += 256) sPK[i] = PK[b*NVP + i];
    __syncthreads();

    const float* o0 = obj + (b*NOBJ + n0)*3;
    const float* o1 = obj + (b*NOBJ + n1)*3;
    float ox0 = o0[0], oy0 = o0[1], oz0 = o0[2];
    float ox1 = o1[0], oy1 = o1[1], oz1 = o1[2];

    // chunk A: [0,390), chunk B: [390,780) (sentinels in B)
    float sA0 = 1e30f, sB0 = 1e30f, sA1 = 1e30f, sB1 = 1e30f;
    int   jA0 = 0,     jB0 = 390,   jA1 = 0,     jB1 = 390;
    #pragma unroll 2
    for (int j = 0; j < 390; ++j) {
        float4 va = sPK[j];
        float4 vb = sPK[j + 390];
        {
            float s = fmaf(-ox0, va.x, va.w); s = fmaf(-oy0, va.y, s); s = fmaf(-oz0, va.z, s);
            if (s < sA0) { sA0 = s; jA0 = j; }
        }
        {
            float s = fmaf(-ox0, vb.x, vb.w); s = fmaf(-oy0, vb.y, s); s = fmaf(-oz0, vb.z, s);
            if (s < sB0) { sB0 = s; jB0 = j + 390; }
        }
        {
            float s = fmaf(-ox1, va.x, va.w); s = fmaf(-oy1, va.y, s); s = fmaf(-oz1, va.z, s);
            if (s < sA1) { sA1 = s; jA1 = j; }
        }
        {
            float s = fmaf(-ox1, vb.x, vb.w); s = fmaf(-oy1, vb.y, s); s = fmaf(-oz1, vb.z, s);
            if (s < sB1) { sB1 = s; jB1 = j + 390; }
        }
    }
    // ascending-index combine, strict < => first-index tie-break
    if (sB0 < sA0) { sA0 = sB0; jA0 = jB0; }
    if (sB1 < sA1) { sA1 = sB1; jA1 = jB1; }

    // ---- point 0 epilogue
    float osq0 = ox0*ox0 + oy0*oy0 + oz0*oz0;
    float d20 = 2.0f * sA0 + osq0;
    cmap[b*NOBJ + n0] = 2.0f / (1.0f + __expf(100.0f * d20));
    float4 q0 = sPK[jA0];
    float nx0 = NRM[(base + jA0)*3 + 0];
    float ny0 = NRM[(base + jA0)*3 + 1];
    float nz0 = NRM[(base + jA0)*3 + 2];
    float dp0 = (q0.x - ox0)*nx0 + (q0.y - oy0)*ny0 + (q0.z - oz0)*nz0;
    float p = (dp0 > 0.0f) ? d20 : 0.0f;

    // ---- point 1 epilogue
    float osq1 = ox1*ox1 + oy1*oy1 + oz1*oz1;
    float d21 = 2.0f * sA1 + osq1;
    cmap[b*NOBJ + n1] = 2.0f / (1.0f + __expf(100.0f * d21));
    float4 q1 = sPK[jA1];
    float nx1 = NRM[(base + jA1)*3 + 0];
    float ny1 = NRM[(base + jA1)*3 + 1];
    float nz1 = NRM[(base + jA1)*3 + 2];
    float dp1 = (q1.x - ox1)*nx1 + (q1.y - oy1)*ny1 + (q1.z - oz1)*nz1;
    p += (dp1 > 0.0f) ? d21 : 0.0f;

    for (int off = 32; off; off >>= 1) p += __shfl_down(p, off, 64);
    __shared__ float wsum[4];
    if (lane == 0) wsum[t >> 6] = p;
    __syncthreads();
    if (t == 0) atomicAdd(pen, (wsum[0] + wsum[1] + wsum[2] + wsum[3]) * (1.0f / NB));
}

extern "C" void kernel_launch(void* const* d_in, const int* in_sizes, int n_in,
                              void* d_out, int out_size, void* d_ws, size_t ws_size,
                              hipStream_t stream)
{
    const float* hp    = (const float*)d_in[0];
    const float* obj   = (const float*)d_in[1];
    const float* beta  = (const float*)d_in[2];
    const float* vt    = (const float*)d_in[3];
    const float* sd    = (const float*)d_in[4];
    const float* pd    = (const float*)d_in[5];
    const float* Jreg  = (const float*)d_in[6];
    const float* W     = (const float*)d_in[7];
    const float* pca   = (const float*)d_in[8];
    const float* aw    = (const float*)d_in[9];
    const int*   faces = (const int*)d_in[10];
    const int*   afi   = (const int*)d_in[11];

    float* out     = (float*)d_out;
    float* cmap    = out;                          // 131072
    float* pen     = out + NB*NOBJ;                // 1
    float* verts   = out + NB*NOBJ + 1;            // 18672
    float* contact = out + NB*NOBJ + 1 + NB*NV*3;  // 768

    float* ws   = (float*)d_ws;
    float4* PK  = (float4*)ws;        // NB*NVP float4 (16B-aligned at base)
    float* NRM  = ws + NB*NVP*4;      // NB*VD
    float* VS   = NRM + NB*VD;        // NB*VD
    float* VP   = VS + NB*VD;         // NB*VD
    float* sRg  = VP + NB*VD;         // NB*144

    k_blend<<<NB*BCH, 256, 0, stream>>>(hp, pca, vt, sd, pd, beta, VS, VP, sRg, pen);
    k_skel <<<NB, 1024, 0, stream>>>(hp, sRg, Jreg, VS, VP, W, faces, aw, afi,
                                     verts, PK, NRM, contact);
    k_nn   <<<NB*32, 256, 0, stream>>>(obj, PK, NRM, cmap, pen);
}

// Round 5
// 146.503 us; speedup vs baseline: 1.2981x; 1.0089x over previous
//
#include <hip/hip_runtime.h>
#include <math.h>

#define NV 778
#define NJ 16
#define NCOMP 24
#define NBETA 10
#define FC 1554
#define NA 32
#define NB 8
#define NOBJ 16384
#define VD (NV*3)          // 2334
#define BCH 584            // ceil(VD/4) row-chunks per batch for k_blend
#define CH 392             // NN chunk length
#define NVL 792            // LDS vertex slots (2*CH + prefetch pad)

// ---------------- Kernel 1: fused pose + blendshapes (proven; sRg export dropped).
__global__ __launch_bounds__(256) void k_blend(
    const float* __restrict__ hp, const float* __restrict__ pca,
    const float* __restrict__ vt, const float* __restrict__ sd,
    const float* __restrict__ pd, const float* __restrict__ beta,
    float* __restrict__ VS, float* __restrict__ VP, float* __restrict__ pen)
{
    int b = blockIdx.x / BCH, c = blockIdx.x % BCH;
    int t = threadIdx.x;
    int wid = t >> 6, lane = t & 63;
    __shared__ float h45[45];
    __shared__ float sR[NJ*9];
    __shared__ float spf[135];

    if (t < 45) {
        float acc = 0.0f;
        #pragma unroll
        for (int k = 0; k < NCOMP; ++k) acc += hp[b*30 + 6 + k] * pca[k*45 + t];
        h45[t] = acc;
    }
    __syncthreads();
    if (t < NJ) {
        float rx, ry, rz;
        if (t == 0) { rx = hp[b*30+3]; ry = hp[b*30+4]; rz = hp[b*30+5]; }
        else        { rx = h45[(t-1)*3]; ry = h45[(t-1)*3+1]; rz = h45[(t-1)*3+2]; }
        float th = sqrtf(rx*rx + ry*ry + rz*rz + 1e-16f);
        float kx = rx/th, ky = ry/th, kz = rz/th;
        float cc = cosf(th), s = sinf(th), o = 1.0f - cc;
        float R[9];
        R[0] = cc + o*kx*kx;     R[1] = -s*kz + o*kx*ky;  R[2] =  s*ky + o*kx*kz;
        R[3] =  s*kz + o*ky*kx;  R[4] = cc + o*ky*ky;     R[5] = -s*kx + o*ky*kz;
        R[6] = -s*ky + o*kz*kx;  R[7] =  s*kx + o*kz*ky;  R[8] = cc + o*kz*kz;
        #pragma unroll
        for (int i = 0; i < 9; ++i) sR[t*9+i] = R[i];
    }
    __syncthreads();
    if (t < 135) {
        int mn = t % 9;
        float d = (mn == 0 || mn == 4 || mn == 8) ? 1.0f : 0.0f;
        spf[t] = sR[9 + t] - d;
    }
    if (b == 0 && c == 0 && t == 0) *pen = 0.0f;
    __syncthreads();

    int r = c*4 + wid;                 // row within batch: v*3 + d
    if (r < VD) {
        const float* p  = pd + r * 135;
        float accP = p[lane] * spf[lane] + p[lane+64] * spf[lane+64];
        accP += (lane < 7) ? p[lane+128] * spf[lane+128] : 0.0f;

        float accS = (lane < NBETA) ? sd[r*NBETA + lane] * beta[b*NBETA + lane] : 0.0f;

        #pragma unroll
        for (int off = 32; off; off >>= 1) {
            accP += __shfl_down(accP, off, 64);
            accS += __shfl_down(accS, off, 64);
        }
        if (lane == 0) {
            float vs = vt[r] + accS;
            VS[b*VD + r] = vs;
            VP[b*VD + r] = vs + accP;
        }
    }
}

// ---------------- Kernel 2: MEGA — redundant skeleton prelude + pipelined NN.
// 256 blocks (1/CU), 32 blocks per batch; each block rebuilds its batch's
// skeleton/verts/normals in LDS (~2 us redundant work) and then runs the NN
// scan for its 512 object points (2/thread). Kills the separate k_skel
// launch, its 8-CU-only runtime, and the PK/NRM global round-trips.
__global__ __launch_bounds__(256) void k_mega(
    const float* __restrict__ hp, const float* __restrict__ pca,
    const float* __restrict__ Jreg, const float* __restrict__ VS,
    const float* __restrict__ VP, const float* __restrict__ W,
    const int* __restrict__ faces, const float* __restrict__ aw,
    const int* __restrict__ afi, const float* __restrict__ obj,
    float* __restrict__ verts, float* __restrict__ cmap,
    float* __restrict__ contact, float* __restrict__ pen)
{
    int blk = blockIdx.x;
    int b = blk >> 5;                 // batch
    int g = blk & 31;                 // point-group within batch
    int t = threadIdx.x, lane = t & 63, wid = t >> 6;

    __shared__ float4 sPK[NVL];       // {x,y,z,0.5*|v|^2}; 778..791 sentinels
    __shared__ float sv[VD];
    __shared__ float sn[VD];
    __shared__ float sR[NJ*9];
    __shared__ float sJ[NJ*3];
    __shared__ float4 sA4[NJ*3];
    __shared__ float h45[45];
    __shared__ float wsum[4];

    // object points for the NN phase: load first, hide HBM latency behind prelude
    int n0 = g*512 + t;
    int n1 = n0 + 256;
    const float* o0p = obj + (b*NOBJ + n0)*3;
    const float* o1p = obj + (b*NOBJ + n1)*3;
    float ox0 = o0p[0], oy0 = o0p[1], oz0 = o0p[2];
    float ox1 = o1p[0], oy1 = o1p[1], oz1 = o1p[2];

    // ---- pose preamble (PCA matvec + Rodrigues)
    if (t < 45) {
        float acc = 0.0f;
        #pragma unroll
        for (int k = 0; k < NCOMP; ++k) acc += hp[b*30 + 6 + k] * pca[k*45 + t];
        h45[t] = acc;
    }
    for (int i = t; i < VD; i += 256) sn[i] = 0.0f;
    if (t < NVL - NV) sPK[NV + t] = make_float4(0.f, 0.f, 0.f, 1e30f);
    __syncthreads();
    if (t < NJ) {
        float rx, ry, rz;
        if (t == 0) { rx = hp[b*30+3]; ry = hp[b*30+4]; rz = hp[b*30+5]; }
        else        { rx = h45[(t-1)*3]; ry = h45[(t-1)*3+1]; rz = h45[(t-1)*3+2]; }
        float th = sqrtf(rx*rx + ry*ry + rz*rz + 1e-16f);
        float kx = rx/th, ky = ry/th, kz = rz/th;
        float cc = cosf(th), s = sinf(th), o = 1.0f - cc;
        sR[t*9+0] = cc + o*kx*kx;     sR[t*9+1] = -s*kz + o*kx*ky;  sR[t*9+2] =  s*ky + o*kx*kz;
        sR[t*9+3] =  s*kz + o*ky*kx;  sR[t*9+4] = cc + o*ky*ky;     sR[t*9+5] = -s*kx + o*ky*kz;
        sR[t*9+6] = -s*ky + o*kz*kx;  sR[t*9+7] =  s*kx + o*kz*ky;  sR[t*9+8] = cc + o*kz*kz;
    }
    __syncthreads();

    // ---- joints: wave wid handles joints 4*wid..4*wid+3
    {
        float ac[12];
        #pragma unroll
        for (int q = 0; q < 12; ++q) ac[q] = 0.0f;
        for (int v = lane; v < NV; v += 64) {
            const float* p = VS + b*VD + v*3;
            float x = p[0], y = p[1], z = p[2];
            #pragma unroll
            for (int jj = 0; jj < 4; ++jj) {
                float w = Jreg[(4*wid + jj)*NV + v];
                ac[jj*3+0] += w*x; ac[jj*3+1] += w*y; ac[jj*3+2] += w*z;
            }
        }
        #pragma unroll
        for (int q = 0; q < 12; ++q)
            for (int off = 32; off; off >>= 1) ac[q] += __shfl_down(ac[q], off, 64);
        if (lane == 0) {
            #pragma unroll
            for (int q = 0; q < 12; ++q) sJ[(4*wid + q/3)*3 + (q%3)] = ac[q];
        }
    }
    __syncthreads();

    // ---- kinematic chain: thread m (0..2) owns row m of all transforms
    if (t < 3) {
        const int par[NJ] = {-1,0,1,2,0,4,5,0,7,8,0,10,11,0,13,14};
        int m = t;
        float Tr[NJ][3], Tt[NJ];
        Tr[0][0] = sR[m*3+0]; Tr[0][1] = sR[m*3+1]; Tr[0][2] = sR[m*3+2];
        Tt[0] = sJ[m];
        #pragma unroll
        for (int j = 1; j < NJ; ++j) {
            int p = par[j];
            float t0 = sJ[j*3+0] - sJ[p*3+0];
            float t1 = sJ[j*3+1] - sJ[p*3+1];
            float t2 = sJ[j*3+2] - sJ[p*3+2];
            float a0 = Tr[p][0], a1 = Tr[p][1], a2 = Tr[p][2];
            #pragma unroll
            for (int n = 0; n < 3; ++n)
                Tr[j][n] = a0*sR[j*9+n] + a1*sR[j*9+3+n] + a2*sR[j*9+6+n];
            Tt[j] = a0*t0 + a1*t1 + a2*t2 + Tt[p];
        }
        #pragma unroll
        for (int j = 0; j < NJ; ++j) {
            float corr = Tr[j][0]*sJ[j*3] + Tr[j][1]*sJ[j*3+1] + Tr[j][2]*sJ[j*3+2];
            sA4[j*3 + m] = make_float4(Tr[j][0], Tr[j][1], Tr[j][2], Tt[j] - corr);
        }
    }
    __syncthreads();

    // ---- LBS into sv + sPK (block g==0 also writes verts out)
    float tx = hp[b*30+0], ty = hp[b*30+1], tz = hp[b*30+2];
    for (int v = t; v < NV; v += 256) {
        float4 r0 = make_float4(0,0,0,0), r1 = make_float4(0,0,0,0), r2 = make_float4(0,0,0,0);
        const float* w = W + v * NJ;
        for (int j = 0; j < NJ; ++j) {
            float wj = w[j];
            float4 A0 = sA4[j*3+0], A1 = sA4[j*3+1], A2 = sA4[j*3+2];
            r0.x += wj*A0.x; r0.y += wj*A0.y; r0.z += wj*A0.z; r0.w += wj*A0.w;
            r1.x += wj*A1.x; r1.y += wj*A1.y; r1.z += wj*A1.z; r1.w += wj*A1.w;
            r2.x += wj*A2.x; r2.y += wj*A2.y; r2.z += wj*A2.z; r2.w += wj*A2.w;
        }
        float px = VP[b*VD + v*3], py = VP[b*VD + v*3+1], pz = VP[b*VD + v*3+2];
        float x = r0.x*px + r0.y*py + r0.z*pz + r0.w + tx;
        float y = r1.x*px + r1.y*py + r1.z*pz + r1.w + ty;
        float z = r2.x*px + r2.y*py + r2.z*pz + r2.w + tz;
        sv[v*3] = x; sv[v*3+1] = y; sv[v*3+2] = z;
        sPK[v] = make_float4(x, y, z, 0.5f*(x*x + y*y + z*z));
        if (g == 0) {
            int i = b*NV + v;
            verts[i*3] = x; verts[i*3+1] = y; verts[i*3+2] = z;
        }
    }
    __syncthreads();

    // ---- face normals into LDS accumulator
    for (int f = t; f < FC; f += 256) {
        int i0 = faces[f*3], i1 = faces[f*3+1], i2 = faces[f*3+2];
        float ax = sv[i1*3+0]-sv[i0*3+0], ay = sv[i1*3+1]-sv[i0*3+1], az = sv[i1*3+2]-sv[i0*3+2];
        float bx = sv[i2*3+0]-sv[i0*3+0], by = sv[i2*3+1]-sv[i0*3+1], bz = sv[i2*3+2]-sv[i0*3+2];
        float cx = ay*bz - az*by, cy = az*bx - ax*bz, cz = ax*by - ay*bx;
        atomicAdd(&sn[i0*3+0], cx); atomicAdd(&sn[i0*3+1], cy); atomicAdd(&sn[i0*3+2], cz);
        atomicAdd(&sn[i1*3+0], cx); atomicAdd(&sn[i1*3+1], cy); atomicAdd(&sn[i1*3+2], cz);
        atomicAdd(&sn[i2*3+0], cx); atomicAdd(&sn[i2*3+1], cy); atomicAdd(&sn[i2*3+2], cz);
    }
    __syncthreads();

    // ---- contact candidates (one block per batch)
    if (g == 0 && t < NA*3) {
        int a = t / 3, d = t % 3;
        float acc = 0.0f;
        #pragma unroll
        for (int k = 0; k < 3; ++k)
            acc += aw[a*3 + k] * sv[afi[a*3 + k]*3 + d];
        contact[b*NA*3 + t] = acc;
    }

    // ---- NN phase: 2 points/thread, 2 chunks, depth-2 software pipeline.
    // chunk A = [0,392), chunk B = [392,784) (sentinels at 778..783);
    // ascending-chunk strict-< combine preserves jnp.argmin first-index.
    float sA0 = 1e30f, sB0 = 1e30f, sA1 = 1e30f, sB1 = 1e30f;
    int   jA0 = 0,     jB0 = CH,    jA1 = 0,     jB1 = CH;

    float4 a0 = sPK[0],  b0 = sPK[CH];
    float4 a1 = sPK[1],  b1 = sPK[CH+1];
    #pragma unroll 2
    for (int j = 0; j < CH; ++j) {
        float4 a2 = sPK[j+2];        // prefetch depth 2 (max idx 393)
        float4 b2 = sPK[j+CH+2];     // (max idx 785 < NVL)
        {
            float s = fmaf(-ox0, a0.x, a0.w); s = fmaf(-oy0, a0.y, s); s = fmaf(-oz0, a0.z, s);
            if (s < sA0) { sA0 = s; jA0 = j; }
        }
        {
            float s = fmaf(-ox0, b0.x, b0.w); s = fmaf(-oy0, b0.y, s); s = fmaf(-oz0, b0.z, s);
            if (s < sB0) { sB0 = s; jB0 = j + CH; }
        }
        {
            float s = fmaf(-ox1, a0.x, a0.w); s = fmaf(-oy1, a0.y, s); s = fmaf(-oz1, a0.z, s);
            if (s < sA1) { sA1 = s; jA1 = j; }
        }
        {
            float s = fmaf(-ox1, b0.x, b0.w); s = fmaf(-oy1, b0.y, s); s = fmaf(-oz1, b0.z, s);
            if (s < sB1) { sB1 = s; jB1 = j + CH; }
        }
        a0 = a1; b0 = b1; a1 = a2; b1 = b2;
    }
    if (sB0 < sA0) { sA0 = sB0; jA0 = jB0; }
    if (sB1 < sA1) { sA1 = sB1; jA1 = jB1; }

    // ---- epilogues (normals from LDS)
    float osq0 = ox0*ox0 + oy0*oy0 + oz0*oz0;
    float d20 = 2.0f * sA0 + osq0;
    cmap[b*NOBJ + n0] = 2.0f / (1.0f + __expf(100.0f * d20));
    float4 q0 = sPK[jA0];
    float dp0 = (q0.x - ox0)*sn[jA0*3+0] + (q0.y - oy0)*sn[jA0*3+1] + (q0.z - oz0)*sn[jA0*3+2];
    float p = (dp0 > 0.0f) ? d20 : 0.0f;

    float osq1 = ox1*ox1 + oy1*oy1 + oz1*oz1;
    float d21 = 2.0f * sA1 + osq1;
    cmap[b*NOBJ + n1] = 2.0f / (1.0f + __expf(100.0f * d21));
    float4 q1 = sPK[jA1];
    float dp1 = (q1.x - ox1)*sn[jA1*3+0] + (q1.y - oy1)*sn[jA1*3+1] + (q1.z - oz1)*sn[jA1*3+2];
    p += (dp1 > 0.0f) ? d21 : 0.0f;

    for (int off = 32; off; off >>= 1) p += __shfl_down(p, off, 64);
    if (lane == 0) wsum[wid] = p;
    __syncthreads();
    if (t == 0) atomicAdd(pen, (wsum[0] + wsum[1] + wsum[2] + wsum[3]) * (1.0f / NB));
}

extern "C" void kernel_launch(void* const* d_in, const int* in_sizes, int n_in,
                              void* d_out, int out_size, void* d_ws, size_t ws_size,
                              hipStream_t stream)
{
    const float* hp    = (const float*)d_in[0];
    const float* obj   = (const float*)d_in[1];
    const float* beta  = (const float*)d_in[2];
    const float* vt    = (const float*)d_in[3];
    const float* sd    = (const float*)d_in[4];
    const float* pd    = (const float*)d_in[5];
    const float* Jreg  = (const float*)d_in[6];
    const float* W     = (const float*)d_in[7];
    const float* pca   = (const float*)d_in[8];
    const float* aw    = (const float*)d_in[9];
    const int*   faces = (const int*)d_in[10];
    const int*   afi   = (const int*)d_in[11];

    float* out     = (float*)d_out;
    float* cmap    = out;                          // 131072
    float* pen     = out + NB*NOBJ;                // 1
    float* verts   = out + NB*NOBJ + 1;            // 18672
    float* contact = out + NB*NOBJ + 1 + NB*NV*3;  // 768

    float* ws   = (float*)d_ws;
    float* VS   = ws;                 // NB*VD
    float* VP   = VS + NB*VD;         // NB*VD

    k_blend<<<NB*BCH, 256, 0, stream>>>(hp, pca, vt, sd, pd, beta, VS, VP, pen);
    k_mega <<<NB*32, 256, 0, stream>>>(hp, pca, Jreg, VS, VP, W, faces, aw, afi,
                                       obj, verts, cmap, contact, pen);
}